// Round 5
// baseline (492.591 us; speedup 1.0000x reference)
//
#include <hip/hip_runtime.h>
#include <math.h>

#define GG 128
#define NPER 512
#define KK 30
#define NN (GG*NPER)        // 65536
#define EE 1048576
#define DIN0 96
#define DL 32
#define TOTAL 97
#define C1C 16
#define C2C 32
#define KW2C 5
#define POOL_LEN 15
#define CONV_OUT 11
#define DENSE 352
#define OUTD 128
#define PB_CAP 6144

typedef unsigned long long u64;
typedef unsigned int u32;

// ================= P0: per-block partial bucket histograms (no global atomics, no memset) =================
__global__ __launch_bounds__(256) void k_bhist(const int* __restrict__ dst, int* __restrict__ bpart) {
    __shared__ int h[256];
    int t = threadIdx.x;
    h[t] = 0;
    __syncthreads();
    int base = blockIdx.x * 4096;
    for (int i = t; i < 4096; i += 256) atomicAdd(&h[dst[base + i] >> 8], 1);
    __syncthreads();
    bpart[blockIdx.x * 256 + t] = h[t];
}

// ================= P0b: sum partials + scan -> bbase[257], bcur =================
__global__ __launch_bounds__(256) void k_bscan(const int* __restrict__ bpart,
                                               int* __restrict__ bbase, int* __restrict__ bcur) {
    __shared__ int sc[2][256];
    int t = threadIdx.x;
    int v0 = 0;
    for (int b = 0; b < 256; ++b) v0 += bpart[b * 256 + t];
    sc[0][t] = v0;
    __syncthreads();
    int c = 0;
    for (int off = 1; off < 256; off <<= 1) {
        int v = sc[c][t];
        if (t >= off) v += sc[c][t - off];
        sc[c ^ 1][t] = v;
        __syncthreads();
        c ^= 1;
    }
    int incl = sc[c][t];
    bbase[t] = incl - v0;
    bcur[t]  = incl - v0;
    if (t == 255) bbase[256] = incl;
}

// packed: bkt(8b)<<44 | eid(20b)<<24 | src(16b)<<8 | dstloc(8b)
__global__ __launch_bounds__(256) void k_bucket(const int* __restrict__ src, const int* __restrict__ dst,
                                                int* __restrict__ bcur, u64* __restrict__ bedges) {
    __shared__ u64 stage[4096];
    __shared__ int hist[256], sc[2][256], excl[256], cur[256], runbase[256];
    int t = threadIdx.x;
    hist[t] = 0; cur[t] = 0;
    __syncthreads();
    int base = blockIdx.x * 4096;
    u64 r[16];
    #pragma unroll
    for (int i = 0; i < 16; ++i) {
        int e = base + t + i * 256;
        int d = dst[e], s = src[e];
        int bkt = d >> 8;
        r[i] = ((u64)bkt << 44) | ((u64)e << 24) | ((u64)s << 8) | (u64)(d & 255);
        atomicAdd(&hist[bkt], 1);
    }
    __syncthreads();
    sc[0][t] = hist[t];
    __syncthreads();
    int c = 0;
    for (int off = 1; off < 256; off <<= 1) {
        int v = sc[c][t];
        if (t >= off) v += sc[c][t - off];
        sc[c ^ 1][t] = v;
        __syncthreads();
        c ^= 1;
    }
    excl[t] = sc[c][t] - hist[t];
    runbase[t] = atomicAdd(&bcur[t], hist[t]);
    __syncthreads();
    #pragma unroll
    for (int i = 0; i < 16; ++i) {
        int bkt = (int)(r[i] >> 44);
        int li = excl[bkt] + atomicAdd(&cur[bkt], 1);
        stage[li] = r[i];
    }
    __syncthreads();
    for (int idx = t; idx < 4096; idx += 256) {
        u64 p = stage[idx];
        int bkt = (int)(p >> 44);
        bedges[runbase[bkt] + (idx - excl[bkt])] = p;
    }
}

// ================= fused per-bucket: CSR + e2n gather + layer0 matmul =================
__global__ __launch_bounds__(256) void k_csr_e2n_l0(const u64* __restrict__ bedges, const int* __restrict__ bbase,
                                                    const float* __restrict__ edge_feat,
                                                    const float* __restrict__ node_feat,
                                                    const float* __restrict__ W0,
                                                    int* __restrict__ rowptr, float* __restrict__ degf,
                                                    int* __restrict__ s_src, float* __restrict__ yA) {
    __shared__ u32 eids[PB_CAP];           // sorted-by-dstloc eid list (24 KB)
    __shared__ int hist[256], sc[2][256], excl[256], cur[256];
    __shared__ float e2n_l[256][33];       // 33 KB
    __shared__ float W0l[DIN0 * DL];       // 12 KB
    __shared__ float nf[32][65];           // 8.3 KB
    int t = threadIdx.x, b = blockIdx.x;
    hist[t] = 0; cur[t] = 0;
    for (int i = t; i < DIN0 * DL; i += 256) W0l[i] = W0[i];
    __syncthreads();
    int beg = bbase[b], end = bbase[b + 1];
    int cnt = end - beg;

    // pass 1: local histogram over dstloc
    for (int j = t; j < cnt; j += 256)
        atomicAdd(&hist[(int)(bedges[beg + j] & 255)], 1);
    __syncthreads();
    sc[0][t] = hist[t];
    __syncthreads();
    int c = 0;
    for (int off = 1; off < 256; off <<= 1) {
        int v = sc[c][t];
        if (t >= off) v += sc[c][t - off];
        sc[c ^ 1][t] = v;
        __syncthreads();
        c ^= 1;
    }
    excl[t] = sc[c][t] - hist[t];
    int n = b * 256 + t;
    rowptr[n] = beg + excl[t];
    degf[n] = (float)hist[t] + 1.0f;
    if (b == 255 && t == 255) rowptr[NN] = EE;
    __syncthreads();

    // pass 2: scatter s_src (global) + sorted eid list (LDS)
    for (int j = t; j < cnt; j += 256) {
        u64 p = bedges[beg + j];
        int dl = (int)(p & 255);
        int pos = excl[dl] + atomicAdd(&cur[dl], 1);
        s_src[beg + pos] = (int)((p >> 8) & 0xFFFF);
        if (pos < PB_CAP) eids[pos] = (u32)((p >> 24) & 0xFFFFF);
    }
    __syncthreads();

    // pass 3: e2n gather into LDS (8 lanes per node, 32 nodes per sweep)
    const float4* ef4 = (const float4*)edge_feat;
    int l = t & 7;
    for (int p8 = 0; p8 < 8; ++p8) {
        int nl = p8 * 32 + (t >> 3);
        int jb = excl[nl];
        int je = jb + hist[nl];
        if (je > PB_CAP) je = PB_CAP;   // unreachable for this input
        float4 s = make_float4(0.f, 0.f, 0.f, 0.f);
        for (int j = jb; j < je; ++j) {
            float4 v = ef4[(size_t)eids[j] * 8 + l];
            s.x += v.x; s.y += v.y; s.z += v.z; s.w += v.w;
        }
        e2n_l[nl][l * 4 + 0] = s.x;
        e2n_l[nl][l * 4 + 1] = s.y;
        e2n_l[nl][l * 4 + 2] = s.z;
        e2n_l[nl][l * 4 + 3] = s.w;
    }
    __syncthreads();

    // pass 4: layer0 matmul, 32 nodes per sweep
    for (int p8 = 0; p8 < 8; ++p8) {
        int base_n = b * 256 + p8 * 32;
        __syncthreads();
        for (int i = t; i < 2048; i += 256) {
            int row = i >> 6, col = i & 63;
            nf[row][col] = node_feat[(size_t)(base_n + row) * 64 + col];
        }
        __syncthreads();
        int nl = t >> 3;
        int gn = base_n + nl;
        float4 o = make_float4(0.f, 0.f, 0.f, 0.f);
        #pragma unroll
        for (int k = 0; k < 64; ++k) {
            float hv = nf[nl][k];
            o.x += hv * W0l[k * 32 + l * 4 + 0];
            o.y += hv * W0l[k * 32 + l * 4 + 1];
            o.z += hv * W0l[k * 32 + l * 4 + 2];
            o.w += hv * W0l[k * 32 + l * 4 + 3];
        }
        #pragma unroll
        for (int k = 0; k < 32; ++k) {
            float hv = e2n_l[p8 * 32 + nl][k];
            o.x += hv * W0l[(64 + k) * 32 + l * 4 + 0];
            o.y += hv * W0l[(64 + k) * 32 + l * 4 + 1];
            o.z += hv * W0l[(64 + k) * 32 + l * 4 + 2];
            o.w += hv * W0l[(64 + k) * 32 + l * 4 + 3];
        }
        ((float4*)yA)[(size_t)gn * 8 + l] = o;
    }
}

// ================= fused gather + tanh + hcat + next-layer matmul =================
__global__ __launch_bounds__(256) void k_gl(const int* __restrict__ rowptr,
                                            const int* __restrict__ s_src,
                                            const float* __restrict__ degf,
                                            const float* __restrict__ yin,
                                            const float* __restrict__ bprev,
                                            const float* __restrict__ W,     // 32x32 (next layer)
                                            float* __restrict__ hcat, int colbase,
                                            float* __restrict__ yout) {
    __shared__ float Wl[DL * DL];
    __shared__ float hb[32 * 33];
    for (int i = threadIdx.x; i < DL * DL; i += 256) Wl[i] = W[i];
    int t = threadIdx.x;
    int nl = t >> 3, l = t & 7;
    int n = blockIdx.x * 32 + nl;
    int beg = rowptr[n], end = rowptr[n + 1];
    const float4* y4 = (const float4*)yin;
    float4 bb = ((const float4*)bprev)[l];
    float4 s = y4[n * 8 + l];
    s.x += bb.x; s.y += bb.y; s.z += bb.z; s.w += bb.w;
    for (int j = beg; j < end; ++j) {
        float4 v = y4[s_src[j] * 8 + l];
        s.x += v.x; s.y += v.y; s.z += v.z; s.w += v.w;
    }
    float dg = degf[n];
    float4 h;
    h.x = tanhf(s.x / dg); h.y = tanhf(s.y / dg); h.z = tanhf(s.z / dg); h.w = tanhf(s.w / dg);
    *(float4*)&hcat[n * 96 + colbase + l * 4] = h;
    hb[nl * 33 + l * 4 + 0] = h.x;
    hb[nl * 33 + l * 4 + 1] = h.y;
    hb[nl * 33 + l * 4 + 2] = h.z;
    hb[nl * 33 + l * 4 + 3] = h.w;
    __syncthreads();
    float4 o = make_float4(0.f, 0.f, 0.f, 0.f);
    #pragma unroll
    for (int k = 0; k < 32; ++k) {
        float hv = hb[nl * 33 + k];
        o.x += hv * Wl[k * 32 + l * 4 + 0];
        o.y += hv * Wl[k * 32 + l * 4 + 1];
        o.z += hv * Wl[k * 32 + l * 4 + 2];
        o.w += hv * Wl[k * 32 + l * 4 + 3];
    }
    ((float4*)yout)[n * 8 + l] = o;
}

// variant: last 32-wide layer -> hcat cols 64..95 + scalar y3 = h @ W3
__global__ __launch_bounds__(256) void k_gl3(const int* __restrict__ rowptr,
                                             const int* __restrict__ s_src,
                                             const float* __restrict__ degf,
                                             const float* __restrict__ yin,
                                             const float* __restrict__ bprev,
                                             const float* __restrict__ W3,    // 32x1
                                             float* __restrict__ hcat,
                                             float* __restrict__ y3) {
    __shared__ float W3l[32];
    __shared__ float hb[32 * 33];
    if (threadIdx.x < 32) W3l[threadIdx.x] = W3[threadIdx.x];
    int t = threadIdx.x;
    int nl = t >> 3, l = t & 7;
    int n = blockIdx.x * 32 + nl;
    int beg = rowptr[n], end = rowptr[n + 1];
    const float4* y4 = (const float4*)yin;
    float4 bb = ((const float4*)bprev)[l];
    float4 s = y4[n * 8 + l];
    s.x += bb.x; s.y += bb.y; s.z += bb.z; s.w += bb.w;
    for (int j = beg; j < end; ++j) {
        float4 v = y4[s_src[j] * 8 + l];
        s.x += v.x; s.y += v.y; s.z += v.z; s.w += v.w;
    }
    float dg = degf[n];
    float4 h;
    h.x = tanhf(s.x / dg); h.y = tanhf(s.y / dg); h.z = tanhf(s.z / dg); h.w = tanhf(s.w / dg);
    *(float4*)&hcat[n * 96 + 64 + l * 4] = h;
    hb[nl * 33 + l * 4 + 0] = h.x;
    hb[nl * 33 + l * 4 + 1] = h.y;
    hb[nl * 33 + l * 4 + 2] = h.z;
    hb[nl * 33 + l * 4 + 3] = h.w;
    __syncthreads();
    if (t < 32) {
        float s3 = 0.f;
        #pragma unroll
        for (int k = 0; k < 32; ++k) s3 += hb[t * 33 + k] * W3l[k];
        y3[blockIdx.x * 32 + t] = s3;
    }
}

// ================= head: fused final gather + topk + conv stack =================
__global__ __launch_bounds__(512) void k_head(const int* __restrict__ rowptr,
                                              const int* __restrict__ s_src,
                                              const float* __restrict__ y3,
                                              const float* __restrict__ b3,
                                              const float* __restrict__ degf,
                                              const float* __restrict__ hcat,
                                              const float* __restrict__ cw1, const float* __restrict__ cb1,
                                              const float* __restrict__ cw2, const float* __restrict__ cb2,
                                              const float* __restrict__ ow,  const float* __restrict__ ob,
                                              float* __restrict__ out) {
    __shared__ float sv[NPER];
    __shared__ int   si[NPER];
    __shared__ float pooled[KK][TOTAL];
    __shared__ float c1b[C1C][KK];
    __shared__ float p1[C1C][POOL_LEN];
    __shared__ float flat[DENSE];
    int g = blockIdx.x;
    int tid = threadIdx.x;

    {
        int n = g * NPER + tid;
        int beg = rowptr[n], end = rowptr[n + 1];
        float s = y3[n] + b3[0];
        for (int j = beg; j < end; ++j) s += y3[s_src[j]];
        sv[tid] = tanhf(s / degf[n]);
        si[tid] = tid;
    }
    __syncthreads();

    // bitonic sort: descending by value, ties -> ascending index (jax.lax.top_k semantics)
    for (int ksz = 2; ksz <= NPER; ksz <<= 1) {
        for (int j = ksz >> 1; j > 0; j >>= 1) {
            int i = tid;
            int ixj = i ^ j;
            if (ixj > i) {
                float vi = sv[i], vj = sv[ixj];
                int ii = si[i], ij = si[ixj];
                bool b_ji = (vj > vi) || (vj == vi && ij < ii);
                bool up = ((i & ksz) == 0);
                if (up ? b_ji : !b_ji) {
                    sv[i] = vj; sv[ixj] = vi;
                    si[i] = ij; si[ixj] = ii;
                }
            }
            __syncthreads();
        }
    }

    for (int t = tid; t < KK * TOTAL; t += 512) {
        int k = t / TOTAL, d = t - k * TOTAL;
        if (d < 96) {
            int n = g * NPER + si[k];
            pooled[k][d] = hcat[n * 96 + d];
        } else {
            pooled[k][96] = sv[k];
        }
    }
    __syncthreads();

    for (int t = tid; t < C1C * KK; t += 512) {
        int o = t / KK, k = t - o * KK;
        float s = cb1[o];
        for (int d = 0; d < TOTAL; ++d) s += cw1[o * TOTAL + d] * pooled[k][d];
        c1b[o][k] = fmaxf(s, 0.f);
    }
    __syncthreads();

    for (int t = tid; t < C1C * POOL_LEN; t += 512) {
        int o = t / POOL_LEN, x = t - o * POOL_LEN;
        p1[o][x] = fmaxf(c1b[o][2 * x], c1b[o][2 * x + 1]);
    }
    __syncthreads();

    for (int t = tid; t < C2C * CONV_OUT; t += 512) {
        int o = t / CONV_OUT, x = t - o * CONV_OUT;
        float s = cb2[o];
        for (int i = 0; i < C1C; ++i) {
            #pragma unroll
            for (int j = 0; j < KW2C; ++j)
                s += cw2[(o * C1C + i) * KW2C + j] * p1[i][x + j];
        }
        flat[o * CONV_OUT + x] = fmaxf(s, 0.f);
    }
    __syncthreads();

    for (int m = tid; m < OUTD; m += 512) {
        float s = ob[m];
        for (int d = 0; d < DENSE; ++d) s += flat[d] * ow[d * OUTD + m];
        out[g * OUTD + m] = fmaxf(s, 0.f);
    }
}

extern "C" void kernel_launch(void* const* d_in, const int* in_sizes, int n_in,
                              void* d_out, int out_size, void* d_ws, size_t ws_size,
                              hipStream_t stream) {
    const float* node_feat = (const float*)d_in[0];
    const float* edge_feat = (const float*)d_in[1];
    const int*   edge_src  = (const int*)  d_in[2];
    const int*   edge_dst  = (const int*)  d_in[3];
    const float* W0 = (const float*)d_in[4];
    const float* b0 = (const float*)d_in[5];
    const float* W1 = (const float*)d_in[6];
    const float* b1 = (const float*)d_in[7];
    const float* W2 = (const float*)d_in[8];
    const float* b2 = (const float*)d_in[9];
    const float* W3 = (const float*)d_in[10];
    const float* b3 = (const float*)d_in[11];
    const float* cw1 = (const float*)d_in[12];
    const float* cb1 = (const float*)d_in[13];
    const float* cw2 = (const float*)d_in[14];
    const float* cb2 = (const float*)d_in[15];
    const float* ow  = (const float*)d_in[16];
    const float* ob  = (const float*)d_in[17];
    float* outp = (float*)d_out;

    // ---- workspace layout (bedges aliases hcat: consumed by k_csr_e2n_l0 before hcat's first write) ----
    float* ws   = (float*)d_ws;
    float* hcat = ws;                         // N*96
    u64*   bedges = (u64*)ws;                 // E u64 (alias)
    float* yA   = hcat + (size_t)NN * 96;     // N*32
    float* yB   = yA + NN * 32;               // N*32
    float* y3   = yB + NN * 32;               // N
    float* degf = y3 + NN;                    // N
    int* rowptr = (int*)(degf + NN);          // N+1
    int* s_src  = rowptr + NN + 1;            // E
    int* bpart  = s_src + EE;                 // 256*256
    int* bbase  = bpart + 256 * 256;          // 257
    int* bcur   = bbase + 257;                // 256

    // CSR build (bucketed, write-coalesced, no memset needed)
    k_bhist<<<EE / 4096, 256, 0, stream>>>(edge_dst, bpart);
    k_bscan<<<1, 256, 0, stream>>>(bpart, bbase, bcur);
    k_bucket<<<EE / 4096, 256, 0, stream>>>(edge_src, edge_dst, bcur, bedges);

    // fused: per-bucket CSR finalize + e2n gather + layer0 -> yA
    k_csr_e2n_l0<<<256, 256, 0, stream>>>(bedges, bbase, edge_feat, node_feat, W0,
                                          rowptr, degf, s_src, yA);

    // round 1: gather yA (+b0), tanh -> hcat[0..31], matmul W1 -> yB
    k_gl<<<NN / 32, 256, 0, stream>>>(rowptr, s_src, degf, yA, b0, W1, hcat, 0, yB);
    // round 2: gather yB (+b1), tanh -> hcat[32..63], matmul W2 -> yA
    k_gl<<<NN / 32, 256, 0, stream>>>(rowptr, s_src, degf, yB, b1, W2, hcat, 32, yA);
    // round 3: gather yA (+b2), tanh -> hcat[64..95], y3 = h @ W3
    k_gl3<<<NN / 32, 256, 0, stream>>>(rowptr, s_src, degf, yA, b2, W3, hcat, y3);

    // head: fused scalar gather + topk + conv stack
    k_head<<<GG, 512, 0, stream>>>(rowptr, s_src, y3, b3, degf, hcat,
                                   cw1, cb1, cw2, cb2, ow, ob, outp);
}

// Round 6
// 445.095 us; speedup vs baseline: 1.1067x; 1.1067x over previous
//
#include <hip/hip_runtime.h>
#include <math.h>

#define GG 128
#define NPER 512
#define KK 30
#define NN (GG*NPER)        // 65536
#define EE 1048576
#define DIN0 96
#define DL 32
#define TOTAL 97
#define C1C 16
#define C2C 32
#define KW2C 5
#define POOL_LEN 15
#define CONV_OUT 11
#define DENSE 352
#define OUTD 128
#define PB_CAP 6144

typedef unsigned long long u64;
typedef unsigned int u32;

// ================= P0: per-block partial bucket histograms (no global atomics, no memset) =================
__global__ __launch_bounds__(256) void k_bhist(const int* __restrict__ dst, int* __restrict__ bpart) {
    __shared__ int h[256];
    int t = threadIdx.x;
    h[t] = 0;
    __syncthreads();
    int base = blockIdx.x * 4096;
    for (int i = t; i < 4096; i += 256) atomicAdd(&h[dst[base + i] >> 8], 1);
    __syncthreads();
    bpart[blockIdx.x * 256 + t] = h[t];
}

// ================= P0b: sum partials + scan -> bbase[257], bcur =================
__global__ __launch_bounds__(256) void k_bscan(const int* __restrict__ bpart,
                                               int* __restrict__ bbase, int* __restrict__ bcur) {
    __shared__ int sc[2][256];
    int t = threadIdx.x;
    int v0 = 0;
    for (int b = 0; b < 256; ++b) v0 += bpart[b * 256 + t];
    sc[0][t] = v0;
    __syncthreads();
    int c = 0;
    for (int off = 1; off < 256; off <<= 1) {
        int v = sc[c][t];
        if (t >= off) v += sc[c][t - off];
        sc[c ^ 1][t] = v;
        __syncthreads();
        c ^= 1;
    }
    int incl = sc[c][t];
    bbase[t] = incl - v0;
    bcur[t]  = incl - v0;
    if (t == 255) bbase[256] = incl;
}

// packed: bkt(8b)<<44 | eid(20b)<<24 | src(16b)<<8 | dstloc(8b)
__global__ __launch_bounds__(256) void k_bucket(const int* __restrict__ src, const int* __restrict__ dst,
                                                int* __restrict__ bcur, u64* __restrict__ bedges) {
    __shared__ u64 stage[4096];
    __shared__ int hist[256], sc[2][256], excl[256], cur[256], runbase[256];
    int t = threadIdx.x;
    hist[t] = 0; cur[t] = 0;
    __syncthreads();
    int base = blockIdx.x * 4096;
    u64 r[16];
    #pragma unroll
    for (int i = 0; i < 16; ++i) {
        int e = base + t + i * 256;
        int d = dst[e], s = src[e];
        int bkt = d >> 8;
        r[i] = ((u64)bkt << 44) | ((u64)e << 24) | ((u64)s << 8) | (u64)(d & 255);
        atomicAdd(&hist[bkt], 1);
    }
    __syncthreads();
    sc[0][t] = hist[t];
    __syncthreads();
    int c = 0;
    for (int off = 1; off < 256; off <<= 1) {
        int v = sc[c][t];
        if (t >= off) v += sc[c][t - off];
        sc[c ^ 1][t] = v;
        __syncthreads();
        c ^= 1;
    }
    excl[t] = sc[c][t] - hist[t];
    runbase[t] = atomicAdd(&bcur[t], hist[t]);
    __syncthreads();
    #pragma unroll
    for (int i = 0; i < 16; ++i) {
        int bkt = (int)(r[i] >> 44);
        int li = excl[bkt] + atomicAdd(&cur[bkt], 1);
        stage[li] = r[i];
    }
    __syncthreads();
    for (int idx = t; idx < 4096; idx += 256) {
        u64 p = stage[idx];
        int bkt = (int)(p >> 44);
        bedges[runbase[bkt] + (idx - excl[bkt])] = p;
    }
}

// ================= PB: per-bucket local CSR (rowptr, degf, s_src, s_eid) =================
__global__ __launch_bounds__(256) void k_csr(const u64* __restrict__ bedges, const int* __restrict__ bbase,
                                             int* __restrict__ rowptr, float* __restrict__ degf,
                                             int* __restrict__ s_src, int* __restrict__ s_eid) {
    __shared__ u64 stage[PB_CAP];
    __shared__ int hist[256], sc[2][256], excl[256], cur[256];
    int t = threadIdx.x, b = blockIdx.x;
    hist[t] = 0; cur[t] = 0;
    __syncthreads();
    int beg = bbase[b], end = bbase[b + 1];
    int cnt = end - beg;
    for (int j = t; j < cnt; j += 256) {
        u64 p = bedges[beg + j];
        if (j < PB_CAP) stage[j] = p;
        atomicAdd(&hist[(int)(p & 255)], 1);
    }
    __syncthreads();
    sc[0][t] = hist[t];
    __syncthreads();
    int c = 0;
    for (int off = 1; off < 256; off <<= 1) {
        int v = sc[c][t];
        if (t >= off) v += sc[c][t - off];
        sc[c ^ 1][t] = v;
        __syncthreads();
        c ^= 1;
    }
    excl[t] = sc[c][t] - hist[t];
    int n = b * 256 + t;
    rowptr[n] = beg + excl[t];
    degf[n] = (float)hist[t] + 1.0f;
    if (b == 255 && t == 255) rowptr[NN] = EE;
    __syncthreads();
    int lim = cnt < PB_CAP ? cnt : PB_CAP;
    for (int j = t; j < lim; j += 256) {
        u64 p = stage[j];
        int dl = (int)(p & 255);
        int pos = beg + excl[dl] + atomicAdd(&cur[dl], 1);
        s_src[pos] = (int)((p >> 8) & 0xFFFF);
        s_eid[pos] = (int)((p >> 24) & 0xFFFFF);
    }
    for (int j = PB_CAP + t; j < cnt; j += 256) {
        u64 p = bedges[beg + j];
        int dl = (int)(p & 255);
        int pos = beg + excl[dl] + atomicAdd(&cur[dl], 1);
        s_src[pos] = (int)((p >> 8) & 0xFFFF);
        s_eid[pos] = (int)((p >> 24) & 0xFFFFF);
    }
}

// ================= fused e2n gather + layer0 matmul (2048 blocks, 32 nodes each) =================
__global__ __launch_bounds__(256) void k_e2n_l0(const float* __restrict__ edge_feat,
                                                const int* __restrict__ rowptr,
                                                const int* __restrict__ s_eid,
                                                const float* __restrict__ node_feat,
                                                const float* __restrict__ W0,
                                                float* __restrict__ yA) {
    __shared__ float W0l[DIN0 * DL];   // 12 KB
    __shared__ float e2n_l[32][33];    // 4.2 KB
    __shared__ float nf[32][65];       // 8.3 KB
    int t = threadIdx.x;
    for (int i = t; i < DIN0 * DL; i += 256) W0l[i] = W0[i];
    int nl = t >> 3, l = t & 7;
    int n = blockIdx.x * 32 + nl;
    int beg = rowptr[n], end = rowptr[n + 1];
    const float4* ef4 = (const float4*)edge_feat;
    float4 s = make_float4(0.f, 0.f, 0.f, 0.f);
    for (int j = beg; j < end; ++j) {
        float4 v = ef4[(size_t)s_eid[j] * 8 + l];
        s.x += v.x; s.y += v.y; s.z += v.z; s.w += v.w;
    }
    e2n_l[nl][l * 4 + 0] = s.x;
    e2n_l[nl][l * 4 + 1] = s.y;
    e2n_l[nl][l * 4 + 2] = s.z;
    e2n_l[nl][l * 4 + 3] = s.w;
    for (int i = t; i < 2048; i += 256) {
        int row = i >> 6, col = i & 63;
        nf[row][col] = node_feat[(size_t)(blockIdx.x * 32 + row) * 64 + col];
    }
    __syncthreads();
    float4 o = make_float4(0.f, 0.f, 0.f, 0.f);
    #pragma unroll
    for (int k = 0; k < 64; ++k) {
        float hv = nf[nl][k];
        o.x += hv * W0l[k * 32 + l * 4 + 0];
        o.y += hv * W0l[k * 32 + l * 4 + 1];
        o.z += hv * W0l[k * 32 + l * 4 + 2];
        o.w += hv * W0l[k * 32 + l * 4 + 3];
    }
    #pragma unroll
    for (int k = 0; k < 32; ++k) {
        float hv = e2n_l[nl][k];
        o.x += hv * W0l[(64 + k) * 32 + l * 4 + 0];
        o.y += hv * W0l[(64 + k) * 32 + l * 4 + 1];
        o.z += hv * W0l[(64 + k) * 32 + l * 4 + 2];
        o.w += hv * W0l[(64 + k) * 32 + l * 4 + 3];
    }
    ((float4*)yA)[(size_t)n * 8 + l] = o;
}

// ================= fused gather + tanh + hcat + next-layer matmul =================
__global__ __launch_bounds__(256) void k_gl(const int* __restrict__ rowptr,
                                            const int* __restrict__ s_src,
                                            const float* __restrict__ degf,
                                            const float* __restrict__ yin,
                                            const float* __restrict__ bprev,
                                            const float* __restrict__ W,     // 32x32 (next layer)
                                            float* __restrict__ hcat, int colbase,
                                            float* __restrict__ yout) {
    __shared__ float Wl[DL * DL];
    __shared__ float hb[32 * 33];
    for (int i = threadIdx.x; i < DL * DL; i += 256) Wl[i] = W[i];
    int t = threadIdx.x;
    int nl = t >> 3, l = t & 7;
    int n = blockIdx.x * 32 + nl;
    int beg = rowptr[n], end = rowptr[n + 1];
    const float4* y4 = (const float4*)yin;
    float4 bb = ((const float4*)bprev)[l];
    float4 s = y4[n * 8 + l];
    s.x += bb.x; s.y += bb.y; s.z += bb.z; s.w += bb.w;
    for (int j = beg; j < end; ++j) {
        float4 v = y4[s_src[j] * 8 + l];
        s.x += v.x; s.y += v.y; s.z += v.z; s.w += v.w;
    }
    float dg = degf[n];
    float4 h;
    h.x = tanhf(s.x / dg); h.y = tanhf(s.y / dg); h.z = tanhf(s.z / dg); h.w = tanhf(s.w / dg);
    *(float4*)&hcat[n * 96 + colbase + l * 4] = h;
    hb[nl * 33 + l * 4 + 0] = h.x;
    hb[nl * 33 + l * 4 + 1] = h.y;
    hb[nl * 33 + l * 4 + 2] = h.z;
    hb[nl * 33 + l * 4 + 3] = h.w;
    __syncthreads();
    float4 o = make_float4(0.f, 0.f, 0.f, 0.f);
    #pragma unroll
    for (int k = 0; k < 32; ++k) {
        float hv = hb[nl * 33 + k];
        o.x += hv * Wl[k * 32 + l * 4 + 0];
        o.y += hv * Wl[k * 32 + l * 4 + 1];
        o.z += hv * Wl[k * 32 + l * 4 + 2];
        o.w += hv * Wl[k * 32 + l * 4 + 3];
    }
    ((float4*)yout)[n * 8 + l] = o;
}

// variant: last 32-wide layer -> hcat cols 64..95 + scalar y3 = h @ W3
__global__ __launch_bounds__(256) void k_gl3(const int* __restrict__ rowptr,
                                             const int* __restrict__ s_src,
                                             const float* __restrict__ degf,
                                             const float* __restrict__ yin,
                                             const float* __restrict__ bprev,
                                             const float* __restrict__ W3,    // 32x1
                                             float* __restrict__ hcat,
                                             float* __restrict__ y3) {
    __shared__ float W3l[32];
    __shared__ float hb[32 * 33];
    if (threadIdx.x < 32) W3l[threadIdx.x] = W3[threadIdx.x];
    int t = threadIdx.x;
    int nl = t >> 3, l = t & 7;
    int n = blockIdx.x * 32 + nl;
    int beg = rowptr[n], end = rowptr[n + 1];
    const float4* y4 = (const float4*)yin;
    float4 bb = ((const float4*)bprev)[l];
    float4 s = y4[n * 8 + l];
    s.x += bb.x; s.y += bb.y; s.z += bb.z; s.w += bb.w;
    for (int j = beg; j < end; ++j) {
        float4 v = y4[s_src[j] * 8 + l];
        s.x += v.x; s.y += v.y; s.z += v.z; s.w += v.w;
    }
    float dg = degf[n];
    float4 h;
    h.x = tanhf(s.x / dg); h.y = tanhf(s.y / dg); h.z = tanhf(s.z / dg); h.w = tanhf(s.w / dg);
    *(float4*)&hcat[n * 96 + 64 + l * 4] = h;
    hb[nl * 33 + l * 4 + 0] = h.x;
    hb[nl * 33 + l * 4 + 1] = h.y;
    hb[nl * 33 + l * 4 + 2] = h.z;
    hb[nl * 33 + l * 4 + 3] = h.w;
    __syncthreads();
    if (t < 32) {
        float s3 = 0.f;
        #pragma unroll
        for (int k = 0; k < 32; ++k) s3 += hb[t * 33 + k] * W3l[k];
        y3[blockIdx.x * 32 + t] = s3;
    }
}

// ================= head: fused final gather + topk + conv stack =================
__global__ __launch_bounds__(512) void k_head(const int* __restrict__ rowptr,
                                              const int* __restrict__ s_src,
                                              const float* __restrict__ y3,
                                              const float* __restrict__ b3,
                                              const float* __restrict__ degf,
                                              const float* __restrict__ hcat,
                                              const float* __restrict__ cw1, const float* __restrict__ cb1,
                                              const float* __restrict__ cw2, const float* __restrict__ cb2,
                                              const float* __restrict__ ow,  const float* __restrict__ ob,
                                              float* __restrict__ out) {
    __shared__ float sv[NPER];
    __shared__ int   si[NPER];
    __shared__ float pooled[KK][TOTAL];
    __shared__ float c1b[C1C][KK];
    __shared__ float p1[C1C][POOL_LEN];
    __shared__ float flat[DENSE];
    int g = blockIdx.x;
    int tid = threadIdx.x;

    {
        int n = g * NPER + tid;
        int beg = rowptr[n], end = rowptr[n + 1];
        float s = y3[n] + b3[0];
        for (int j = beg; j < end; ++j) s += y3[s_src[j]];
        sv[tid] = tanhf(s / degf[n]);
        si[tid] = tid;
    }
    __syncthreads();

    // bitonic sort: descending by value, ties -> ascending index (jax.lax.top_k semantics)
    for (int ksz = 2; ksz <= NPER; ksz <<= 1) {
        for (int j = ksz >> 1; j > 0; j >>= 1) {
            int i = tid;
            int ixj = i ^ j;
            if (ixj > i) {
                float vi = sv[i], vj = sv[ixj];
                int ii = si[i], ij = si[ixj];
                bool b_ji = (vj > vi) || (vj == vi && ij < ii);
                bool up = ((i & ksz) == 0);
                if (up ? b_ji : !b_ji) {
                    sv[i] = vj; sv[ixj] = vi;
                    si[i] = ij; si[ixj] = ii;
                }
            }
            __syncthreads();
        }
    }

    for (int t = tid; t < KK * TOTAL; t += 512) {
        int k = t / TOTAL, d = t - k * TOTAL;
        if (d < 96) {
            int n = g * NPER + si[k];
            pooled[k][d] = hcat[n * 96 + d];
        } else {
            pooled[k][96] = sv[k];
        }
    }
    __syncthreads();

    for (int t = tid; t < C1C * KK; t += 512) {
        int o = t / KK, k = t - o * KK;
        float s = cb1[o];
        for (int d = 0; d < TOTAL; ++d) s += cw1[o * TOTAL + d] * pooled[k][d];
        c1b[o][k] = fmaxf(s, 0.f);
    }
    __syncthreads();

    for (int t = tid; t < C1C * POOL_LEN; t += 512) {
        int o = t / POOL_LEN, x = t - o * POOL_LEN;
        p1[o][x] = fmaxf(c1b[o][2 * x], c1b[o][2 * x + 1]);
    }
    __syncthreads();

    for (int t = tid; t < C2C * CONV_OUT; t += 512) {
        int o = t / CONV_OUT, x = t - o * CONV_OUT;
        float s = cb2[o];
        for (int i = 0; i < C1C; ++i) {
            #pragma unroll
            for (int j = 0; j < KW2C; ++j)
                s += cw2[(o * C1C + i) * KW2C + j] * p1[i][x + j];
        }
        flat[o * CONV_OUT + x] = fmaxf(s, 0.f);
    }
    __syncthreads();

    for (int m = tid; m < OUTD; m += 512) {
        float s = ob[m];
        for (int d = 0; d < DENSE; ++d) s += flat[d] * ow[d * OUTD + m];
        out[g * OUTD + m] = fmaxf(s, 0.f);
    }
}

extern "C" void kernel_launch(void* const* d_in, const int* in_sizes, int n_in,
                              void* d_out, int out_size, void* d_ws, size_t ws_size,
                              hipStream_t stream) {
    const float* node_feat = (const float*)d_in[0];
    const float* edge_feat = (const float*)d_in[1];
    const int*   edge_src  = (const int*)  d_in[2];
    const int*   edge_dst  = (const int*)  d_in[3];
    const float* W0 = (const float*)d_in[4];
    const float* b0 = (const float*)d_in[5];
    const float* W1 = (const float*)d_in[6];
    const float* b1 = (const float*)d_in[7];
    const float* W2 = (const float*)d_in[8];
    const float* b2 = (const float*)d_in[9];
    const float* W3 = (const float*)d_in[10];
    const float* b3 = (const float*)d_in[11];
    const float* cw1 = (const float*)d_in[12];
    const float* cb1 = (const float*)d_in[13];
    const float* cw2 = (const float*)d_in[14];
    const float* cb2 = (const float*)d_in[15];
    const float* ow  = (const float*)d_in[16];
    const float* ob  = (const float*)d_in[17];
    float* outp = (float*)d_out;

    // ---- workspace layout (bedges aliases hcat: consumed by k_csr before hcat's first write) ----
    float* ws   = (float*)d_ws;
    float* hcat = ws;                         // N*96
    u64*   bedges = (u64*)ws;                 // E u64 (alias)
    float* yA   = hcat + (size_t)NN * 96;     // N*32
    float* yB   = yA + NN * 32;               // N*32
    float* y3   = yB + NN * 32;               // N
    float* degf = y3 + NN;                    // N
    int* rowptr = (int*)(degf + NN);          // N+1
    int* s_src  = rowptr + NN + 1;            // E
    int* s_eid  = s_src + EE;                 // E
    int* bpart  = s_eid + EE;                 // 256*256
    int* bbase  = bpart + 256 * 256;          // 257
    int* bcur   = bbase + 257;                // 256

    // CSR build (bucketed, write-coalesced, no memset needed)
    k_bhist<<<EE / 4096, 256, 0, stream>>>(edge_dst, bpart);
    k_bscan<<<1, 256, 0, stream>>>(bpart, bbase, bcur);
    k_bucket<<<EE / 4096, 256, 0, stream>>>(edge_src, edge_dst, bcur, bedges);
    k_csr<<<256, 256, 0, stream>>>(bedges, bbase, rowptr, degf, s_src, s_eid);

    // fused e2n gather + layer0 -> yA (2048 blocks: full gather parallelism)
    k_e2n_l0<<<NN / 32, 256, 0, stream>>>(edge_feat, rowptr, s_eid, node_feat, W0, yA);

    // round 1: gather yA (+b0), tanh -> hcat[0..31], matmul W1 -> yB
    k_gl<<<NN / 32, 256, 0, stream>>>(rowptr, s_src, degf, yA, b0, W1, hcat, 0, yB);
    // round 2: gather yB (+b1), tanh -> hcat[32..63], matmul W2 -> yA
    k_gl<<<NN / 32, 256, 0, stream>>>(rowptr, s_src, degf, yB, b1, W2, hcat, 32, yA);
    // round 3: gather yA (+b2), tanh -> hcat[64..95], y3 = h @ W3
    k_gl3<<<NN / 32, 256, 0, stream>>>(rowptr, s_src, degf, yA, b2, W3, hcat, y3);

    // head: fused scalar gather + topk + conv stack
    k_head<<<GG, 512, 0, stream>>>(rowptr, s_src, y3, b3, degf, hcat,
                                   cw1, cb1, cw2, cb2, ow, ob, outp);
}

// Round 7
// 408.979 us; speedup vs baseline: 1.2044x; 1.0883x over previous
//
#include <hip/hip_runtime.h>
#include <math.h>

#define GG 128
#define NPER 512
#define KK 30
#define NN (GG*NPER)        // 65536
#define EE 1048576
#define DIN0 96
#define DL 32
#define TOTAL 97
#define C1C 16
#define C2C 32
#define KW2C 5
#define POOL_LEN 15
#define CONV_OUT 11
#define DENSE 352
#define OUTD 128
#define PB_CAP 6144

typedef unsigned long long u64;
typedef unsigned int u32;

#define F4ADD(a, v) { (a).x += (v).x; (a).y += (v).y; (a).z += (v).z; (a).w += (v).w; }

// ================= P0: per-block partial bucket histograms =================
__global__ __launch_bounds__(256) void k_bhist(const int* __restrict__ dst, int* __restrict__ bpart) {
    __shared__ int h[256];
    int t = threadIdx.x;
    h[t] = 0;
    __syncthreads();
    int base = blockIdx.x * 4096;
    for (int i = t; i < 4096; i += 256) atomicAdd(&h[dst[base + i] >> 8], 1);
    __syncthreads();
    bpart[blockIdx.x * 256 + t] = h[t];
}

// ================= P0b: sum partials + scan -> bbase[257], bcur =================
__global__ __launch_bounds__(256) void k_bscan(const int* __restrict__ bpart,
                                               int* __restrict__ bbase, int* __restrict__ bcur) {
    __shared__ int sc[2][256];
    int t = threadIdx.x;
    int v0 = 0;
    for (int b = 0; b < 256; ++b) v0 += bpart[b * 256 + t];
    sc[0][t] = v0;
    __syncthreads();
    int c = 0;
    for (int off = 1; off < 256; off <<= 1) {
        int v = sc[c][t];
        if (t >= off) v += sc[c][t - off];
        sc[c ^ 1][t] = v;
        __syncthreads();
        c ^= 1;
    }
    int incl = sc[c][t];
    bbase[t] = incl - v0;
    bcur[t]  = incl - v0;
    if (t == 255) bbase[256] = incl;
}

// packed: bkt(8b)<<44 | eid(20b)<<24 | src(16b)<<8 | dstloc(8b)
__global__ __launch_bounds__(256) void k_bucket(const int* __restrict__ src, const int* __restrict__ dst,
                                                int* __restrict__ bcur, u64* __restrict__ bedges) {
    __shared__ u64 stage[4096];
    __shared__ int hist[256], sc[2][256], excl[256], cur[256], runbase[256];
    int t = threadIdx.x;
    hist[t] = 0; cur[t] = 0;
    __syncthreads();
    int base = blockIdx.x * 4096;
    u64 r[16];
    #pragma unroll
    for (int i = 0; i < 16; ++i) {
        int e = base + t + i * 256;
        int d = dst[e], s = src[e];
        int bkt = d >> 8;
        r[i] = ((u64)bkt << 44) | ((u64)e << 24) | ((u64)s << 8) | (u64)(d & 255);
        atomicAdd(&hist[bkt], 1);
    }
    __syncthreads();
    sc[0][t] = hist[t];
    __syncthreads();
    int c = 0;
    for (int off = 1; off < 256; off <<= 1) {
        int v = sc[c][t];
        if (t >= off) v += sc[c][t - off];
        sc[c ^ 1][t] = v;
        __syncthreads();
        c ^= 1;
    }
    excl[t] = sc[c][t] - hist[t];
    runbase[t] = atomicAdd(&bcur[t], hist[t]);
    __syncthreads();
    #pragma unroll
    for (int i = 0; i < 16; ++i) {
        int bkt = (int)(r[i] >> 44);
        int li = excl[bkt] + atomicAdd(&cur[bkt], 1);
        stage[li] = r[i];
    }
    __syncthreads();
    for (int idx = t; idx < 4096; idx += 256) {
        u64 p = stage[idx];
        int bkt = (int)(p >> 44);
        bedges[runbase[bkt] + (idx - excl[bkt])] = p;
    }
}

// ================= PB: per-bucket local CSR =================
__global__ __launch_bounds__(256) void k_csr(const u64* __restrict__ bedges, const int* __restrict__ bbase,
                                             int* __restrict__ rowptr, float* __restrict__ degf,
                                             int* __restrict__ s_src, int* __restrict__ s_eid) {
    __shared__ u64 stage[PB_CAP];
    __shared__ int hist[256], sc[2][256], excl[256], cur[256];
    int t = threadIdx.x, b = blockIdx.x;
    hist[t] = 0; cur[t] = 0;
    __syncthreads();
    int beg = bbase[b], end = bbase[b + 1];
    int cnt = end - beg;
    for (int j = t; j < cnt; j += 256) {
        u64 p = bedges[beg + j];
        if (j < PB_CAP) stage[j] = p;
        atomicAdd(&hist[(int)(p & 255)], 1);
    }
    __syncthreads();
    sc[0][t] = hist[t];
    __syncthreads();
    int c = 0;
    for (int off = 1; off < 256; off <<= 1) {
        int v = sc[c][t];
        if (t >= off) v += sc[c][t - off];
        sc[c ^ 1][t] = v;
        __syncthreads();
        c ^= 1;
    }
    excl[t] = sc[c][t] - hist[t];
    int n = b * 256 + t;
    rowptr[n] = beg + excl[t];
    degf[n] = (float)hist[t] + 1.0f;
    if (b == 255 && t == 255) rowptr[NN] = EE;
    __syncthreads();
    int lim = cnt < PB_CAP ? cnt : PB_CAP;
    for (int j = t; j < lim; j += 256) {
        u64 p = stage[j];
        int dl = (int)(p & 255);
        int pos = beg + excl[dl] + atomicAdd(&cur[dl], 1);
        s_src[pos] = (int)((p >> 8) & 0xFFFF);
        s_eid[pos] = (int)((p >> 24) & 0xFFFFF);
    }
    for (int j = PB_CAP + t; j < cnt; j += 256) {
        u64 p = bedges[beg + j];
        int dl = (int)(p & 255);
        int pos = beg + excl[dl] + atomicAdd(&cur[dl], 1);
        s_src[pos] = (int)((p >> 8) & 0xFFFF);
        s_eid[pos] = (int)((p >> 24) & 0xFFFFF);
    }
}

// ================= fused e2n gather + layer0 matmul (MLP unroll x4) =================
__global__ __launch_bounds__(256) void k_e2n_l0(const float* __restrict__ edge_feat,
                                                const int* __restrict__ rowptr,
                                                const int* __restrict__ s_eid,
                                                const float* __restrict__ node_feat,
                                                const float* __restrict__ W0,
                                                float* __restrict__ yA) {
    __shared__ float W0l[DIN0 * DL];   // 12 KB
    __shared__ float e2n_l[32][33];    // 4.2 KB
    __shared__ float nf[32][65];       // 8.3 KB
    int t = threadIdx.x;
    for (int i = t; i < DIN0 * DL; i += 256) W0l[i] = W0[i];
    int nl = t >> 3, l = t & 7;
    int n = blockIdx.x * 32 + nl;
    int beg = rowptr[n], end = rowptr[n + 1];
    const float4* ef4 = (const float4*)edge_feat;
    float4 a0 = make_float4(0.f, 0.f, 0.f, 0.f);
    float4 a1 = a0, a2 = a0, a3 = a0;
    int j = beg;
    int jend4 = beg + ((end - beg) & ~3);
    for (; j < jend4; j += 4) {
        int e0 = s_eid[j + 0], e1 = s_eid[j + 1], e2 = s_eid[j + 2], e3 = s_eid[j + 3];
        float4 v0 = ef4[(size_t)e0 * 8 + l];
        float4 v1 = ef4[(size_t)e1 * 8 + l];
        float4 v2 = ef4[(size_t)e2 * 8 + l];
        float4 v3 = ef4[(size_t)e3 * 8 + l];
        F4ADD(a0, v0); F4ADD(a1, v1); F4ADD(a2, v2); F4ADD(a3, v3);
    }
    for (; j < end; ++j) {
        float4 v = ef4[(size_t)s_eid[j] * 8 + l];
        F4ADD(a0, v);
    }
    F4ADD(a0, a1); F4ADD(a2, a3); F4ADD(a0, a2);
    e2n_l[nl][l * 4 + 0] = a0.x;
    e2n_l[nl][l * 4 + 1] = a0.y;
    e2n_l[nl][l * 4 + 2] = a0.z;
    e2n_l[nl][l * 4 + 3] = a0.w;
    for (int i = t; i < 2048; i += 256) {
        int row = i >> 6, col = i & 63;
        nf[row][col] = node_feat[(size_t)(blockIdx.x * 32 + row) * 64 + col];
    }
    __syncthreads();
    float4 o = make_float4(0.f, 0.f, 0.f, 0.f);
    #pragma unroll
    for (int k = 0; k < 64; ++k) {
        float hv = nf[nl][k];
        o.x += hv * W0l[k * 32 + l * 4 + 0];
        o.y += hv * W0l[k * 32 + l * 4 + 1];
        o.z += hv * W0l[k * 32 + l * 4 + 2];
        o.w += hv * W0l[k * 32 + l * 4 + 3];
    }
    #pragma unroll
    for (int k = 0; k < 32; ++k) {
        float hv = e2n_l[nl][k];
        o.x += hv * W0l[(64 + k) * 32 + l * 4 + 0];
        o.y += hv * W0l[(64 + k) * 32 + l * 4 + 1];
        o.z += hv * W0l[(64 + k) * 32 + l * 4 + 2];
        o.w += hv * W0l[(64 + k) * 32 + l * 4 + 3];
    }
    ((float4*)yA)[(size_t)n * 8 + l] = o;
}

// ================= fused gather + tanh + hcat + next-layer matmul (MLP unroll x4) =================
__global__ __launch_bounds__(256) void k_gl(const int* __restrict__ rowptr,
                                            const int* __restrict__ s_src,
                                            const float* __restrict__ degf,
                                            const float* __restrict__ yin,
                                            const float* __restrict__ bprev,
                                            const float* __restrict__ W,     // 32x32 (next layer)
                                            float* __restrict__ hcat, int colbase,
                                            float* __restrict__ yout) {
    __shared__ float Wl[DL * DL];
    __shared__ float hb[32 * 33];
    for (int i = threadIdx.x; i < DL * DL; i += 256) Wl[i] = W[i];
    int t = threadIdx.x;
    int nl = t >> 3, l = t & 7;
    int n = blockIdx.x * 32 + nl;
    int beg = rowptr[n], end = rowptr[n + 1];
    const float4* y4 = (const float4*)yin;
    float4 bb = ((const float4*)bprev)[l];
    float4 a0 = y4[n * 8 + l];
    F4ADD(a0, bb);
    float4 a1 = make_float4(0.f, 0.f, 0.f, 0.f);
    float4 a2 = a1, a3 = a1;
    int j = beg;
    int jend4 = beg + ((end - beg) & ~3);
    for (; j < jend4; j += 4) {
        int e0 = s_src[j + 0], e1 = s_src[j + 1], e2 = s_src[j + 2], e3 = s_src[j + 3];
        float4 v0 = y4[e0 * 8 + l];
        float4 v1 = y4[e1 * 8 + l];
        float4 v2 = y4[e2 * 8 + l];
        float4 v3 = y4[e3 * 8 + l];
        F4ADD(a0, v0); F4ADD(a1, v1); F4ADD(a2, v2); F4ADD(a3, v3);
    }
    for (; j < end; ++j) {
        float4 v = y4[s_src[j] * 8 + l];
        F4ADD(a0, v);
    }
    F4ADD(a0, a1); F4ADD(a2, a3); F4ADD(a0, a2);
    float dg = degf[n];
    float4 h;
    h.x = tanhf(a0.x / dg); h.y = tanhf(a0.y / dg); h.z = tanhf(a0.z / dg); h.w = tanhf(a0.w / dg);
    *(float4*)&hcat[n * 96 + colbase + l * 4] = h;
    hb[nl * 33 + l * 4 + 0] = h.x;
    hb[nl * 33 + l * 4 + 1] = h.y;
    hb[nl * 33 + l * 4 + 2] = h.z;
    hb[nl * 33 + l * 4 + 3] = h.w;
    __syncthreads();
    float4 o = make_float4(0.f, 0.f, 0.f, 0.f);
    #pragma unroll
    for (int k = 0; k < 32; ++k) {
        float hv = hb[nl * 33 + k];
        o.x += hv * Wl[k * 32 + l * 4 + 0];
        o.y += hv * Wl[k * 32 + l * 4 + 1];
        o.z += hv * Wl[k * 32 + l * 4 + 2];
        o.w += hv * Wl[k * 32 + l * 4 + 3];
    }
    ((float4*)yout)[n * 8 + l] = o;
}

// variant: last 32-wide layer -> hcat cols 64..95 + scalar y3 = h @ W3
__global__ __launch_bounds__(256) void k_gl3(const int* __restrict__ rowptr,
                                             const int* __restrict__ s_src,
                                             const float* __restrict__ degf,
                                             const float* __restrict__ yin,
                                             const float* __restrict__ bprev,
                                             const float* __restrict__ W3,    // 32x1
                                             float* __restrict__ hcat,
                                             float* __restrict__ y3) {
    __shared__ float W3l[32];
    __shared__ float hb[32 * 33];
    if (threadIdx.x < 32) W3l[threadIdx.x] = W3[threadIdx.x];
    int t = threadIdx.x;
    int nl = t >> 3, l = t & 7;
    int n = blockIdx.x * 32 + nl;
    int beg = rowptr[n], end = rowptr[n + 1];
    const float4* y4 = (const float4*)yin;
    float4 bb = ((const float4*)bprev)[l];
    float4 a0 = y4[n * 8 + l];
    F4ADD(a0, bb);
    float4 a1 = make_float4(0.f, 0.f, 0.f, 0.f);
    float4 a2 = a1, a3 = a1;
    int j = beg;
    int jend4 = beg + ((end - beg) & ~3);
    for (; j < jend4; j += 4) {
        int e0 = s_src[j + 0], e1 = s_src[j + 1], e2 = s_src[j + 2], e3 = s_src[j + 3];
        float4 v0 = y4[e0 * 8 + l];
        float4 v1 = y4[e1 * 8 + l];
        float4 v2 = y4[e2 * 8 + l];
        float4 v3 = y4[e3 * 8 + l];
        F4ADD(a0, v0); F4ADD(a1, v1); F4ADD(a2, v2); F4ADD(a3, v3);
    }
    for (; j < end; ++j) {
        float4 v = y4[s_src[j] * 8 + l];
        F4ADD(a0, v);
    }
    F4ADD(a0, a1); F4ADD(a2, a3); F4ADD(a0, a2);
    float dg = degf[n];
    float4 h;
    h.x = tanhf(a0.x / dg); h.y = tanhf(a0.y / dg); h.z = tanhf(a0.z / dg); h.w = tanhf(a0.w / dg);
    *(float4*)&hcat[n * 96 + 64 + l * 4] = h;
    hb[nl * 33 + l * 4 + 0] = h.x;
    hb[nl * 33 + l * 4 + 1] = h.y;
    hb[nl * 33 + l * 4 + 2] = h.z;
    hb[nl * 33 + l * 4 + 3] = h.w;
    __syncthreads();
    if (t < 32) {
        float s3 = 0.f;
        #pragma unroll
        for (int k = 0; k < 32; ++k) s3 += hb[t * 33 + k] * W3l[k];
        y3[blockIdx.x * 32 + t] = s3;
    }
}

// ================= head: fused final gather + topk + conv stack =================
__global__ __launch_bounds__(512) void k_head(const int* __restrict__ rowptr,
                                              const int* __restrict__ s_src,
                                              const float* __restrict__ y3,
                                              const float* __restrict__ b3,
                                              const float* __restrict__ degf,
                                              const float* __restrict__ hcat,
                                              const float* __restrict__ cw1, const float* __restrict__ cb1,
                                              const float* __restrict__ cw2, const float* __restrict__ cb2,
                                              const float* __restrict__ ow,  const float* __restrict__ ob,
                                              float* __restrict__ out) {
    __shared__ float sv[NPER];
    __shared__ int   si[NPER];
    __shared__ float pooled[KK][TOTAL];
    __shared__ float c1b[C1C][KK];
    __shared__ float p1[C1C][POOL_LEN];
    __shared__ float flat[DENSE];
    int g = blockIdx.x;
    int tid = threadIdx.x;

    {
        int n = g * NPER + tid;
        int beg = rowptr[n], end = rowptr[n + 1];
        float s0 = y3[n] + b3[0], s1 = 0.f, s2 = 0.f, s3 = 0.f;
        int j = beg;
        int jend4 = beg + ((end - beg) & ~3);
        for (; j < jend4; j += 4) {
            float v0 = y3[s_src[j + 0]];
            float v1 = y3[s_src[j + 1]];
            float v2 = y3[s_src[j + 2]];
            float v3 = y3[s_src[j + 3]];
            s0 += v0; s1 += v1; s2 += v2; s3 += v3;
        }
        for (; j < end; ++j) s0 += y3[s_src[j]];
        sv[tid] = tanhf((s0 + s1 + s2 + s3) / degf[n]);
        si[tid] = tid;
    }
    __syncthreads();

    // bitonic sort: descending by value, ties -> ascending index (jax.lax.top_k semantics)
    for (int ksz = 2; ksz <= NPER; ksz <<= 1) {
        for (int j = ksz >> 1; j > 0; j >>= 1) {
            int i = tid;
            int ixj = i ^ j;
            if (ixj > i) {
                float vi = sv[i], vj = sv[ixj];
                int ii = si[i], ij = si[ixj];
                bool b_ji = (vj > vi) || (vj == vi && ij < ii);
                bool up = ((i & ksz) == 0);
                if (up ? b_ji : !b_ji) {
                    sv[i] = vj; sv[ixj] = vi;
                    si[i] = ij; si[ixj] = ii;
                }
            }
            __syncthreads();
        }
    }

    for (int t = tid; t < KK * TOTAL; t += 512) {
        int k = t / TOTAL, d = t - k * TOTAL;
        if (d < 96) {
            int n = g * NPER + si[k];
            pooled[k][d] = hcat[n * 96 + d];
        } else {
            pooled[k][96] = sv[k];
        }
    }
    __syncthreads();

    for (int t = tid; t < C1C * KK; t += 512) {
        int o = t / KK, k = t - o * KK;
        float s = cb1[o];
        for (int d = 0; d < TOTAL; ++d) s += cw1[o * TOTAL + d] * pooled[k][d];
        c1b[o][k] = fmaxf(s, 0.f);
    }
    __syncthreads();

    for (int t = tid; t < C1C * POOL_LEN; t += 512) {
        int o = t / POOL_LEN, x = t - o * POOL_LEN;
        p1[o][x] = fmaxf(c1b[o][2 * x], c1b[o][2 * x + 1]);
    }
    __syncthreads();

    for (int t = tid; t < C2C * CONV_OUT; t += 512) {
        int o = t / CONV_OUT, x = t - o * CONV_OUT;
        float s = cb2[o];
        for (int i = 0; i < C1C; ++i) {
            #pragma unroll
            for (int j = 0; j < KW2C; ++j)
                s += cw2[(o * C1C + i) * KW2C + j] * p1[i][x + j];
        }
        flat[o * CONV_OUT + x] = fmaxf(s, 0.f);
    }
    __syncthreads();

    for (int m = tid; m < OUTD; m += 512) {
        float s = ob[m];
        for (int d = 0; d < DENSE; ++d) s += flat[d] * ow[d * OUTD + m];
        out[g * OUTD + m] = fmaxf(s, 0.f);
    }
}

extern "C" void kernel_launch(void* const* d_in, const int* in_sizes, int n_in,
                              void* d_out, int out_size, void* d_ws, size_t ws_size,
                              hipStream_t stream) {
    const float* node_feat = (const float*)d_in[0];
    const float* edge_feat = (const float*)d_in[1];
    const int*   edge_src  = (const int*)  d_in[2];
    const int*   edge_dst  = (const int*)  d_in[3];
    const float* W0 = (const float*)d_in[4];
    const float* b0 = (const float*)d_in[5];
    const float* W1 = (const float*)d_in[6];
    const float* b1 = (const float*)d_in[7];
    const float* W2 = (const float*)d_in[8];
    const float* b2 = (const float*)d_in[9];
    const float* W3 = (const float*)d_in[10];
    const float* b3 = (const float*)d_in[11];
    const float* cw1 = (const float*)d_in[12];
    const float* cb1 = (const float*)d_in[13];
    const float* cw2 = (const float*)d_in[14];
    const float* cb2 = (const float*)d_in[15];
    const float* ow  = (const float*)d_in[16];
    const float* ob  = (const float*)d_in[17];
    float* outp = (float*)d_out;

    // ---- workspace layout (bedges aliases hcat: consumed by k_csr before hcat's first write) ----
    float* ws   = (float*)d_ws;
    float* hcat = ws;                         // N*96
    u64*   bedges = (u64*)ws;                 // E u64 (alias)
    float* yA   = hcat + (size_t)NN * 96;     // N*32
    float* yB   = yA + NN * 32;               // N*32
    float* y3   = yB + NN * 32;               // N
    float* degf = y3 + NN;                    // N
    int* rowptr = (int*)(degf + NN);          // N+1
    int* s_src  = rowptr + NN + 1;            // E
    int* s_eid  = s_src + EE;                 // E
    int* bpart  = s_eid + EE;                 // 256*256
    int* bbase  = bpart + 256 * 256;          // 257
    int* bcur   = bbase + 257;                // 256

    // CSR build (bucketed, write-coalesced, no memset needed)
    k_bhist<<<EE / 4096, 256, 0, stream>>>(edge_dst, bpart);
    k_bscan<<<1, 256, 0, stream>>>(bpart, bbase, bcur);
    k_bucket<<<EE / 4096, 256, 0, stream>>>(edge_src, edge_dst, bcur, bedges);
    k_csr<<<256, 256, 0, stream>>>(bedges, bbase, rowptr, degf, s_src, s_eid);

    // fused e2n gather + layer0 -> yA (2048 blocks: full gather parallelism)
    k_e2n_l0<<<NN / 32, 256, 0, stream>>>(edge_feat, rowptr, s_eid, node_feat, W0, yA);

    // round 1: gather yA (+b0), tanh -> hcat[0..31], matmul W1 -> yB
    k_gl<<<NN / 32, 256, 0, stream>>>(rowptr, s_src, degf, yA, b0, W1, hcat, 0, yB);
    // round 2: gather yB (+b1), tanh -> hcat[32..63], matmul W2 -> yA
    k_gl<<<NN / 32, 256, 0, stream>>>(rowptr, s_src, degf, yB, b1, W2, hcat, 32, yA);
    // round 3: gather yA (+b2), tanh -> hcat[64..95], y3 = h @ W3
    k_gl3<<<NN / 32, 256, 0, stream>>>(rowptr, s_src, degf, yA, b2, W3, hcat, y3);

    // head: fused scalar gather + topk + conv stack
    k_head<<<GG, 512, 0, stream>>>(rowptr, s_src, y3, b3, degf, hcat,
                                   cw1, cb1, cw2, cb2, ow, ob, outp);
}